// Round 7
// baseline (70.147 us; speedup 1.0000x reference)
//
#include <hip/hip_runtime.h>

// Causal flash-attention forward. B=4, L=2048, H=8, E=64, fp32 in/out.
// Layout: [B, L, H, E] -> ((b*L + l)*H + h)*E + e ; row stride H*E = 512 floats.
//
// prepass: K and V^T -> f16 tiles in d_ws in FRAGMENT-CONSUMPTION order
//   (frag j of a 64x64 tile at tile_base + j*1024 + lane*16).
// main: 512-thread blocks (8 waves, NO barriers). All 8 waves process the SAME
//   128-row q-tile and walk the SAME kv tiles simultaneously reading IDENTICAL
//   addresses -> tile pulled into L1 once, 7 waves hit L1 (L2 traffic /8).
//   Paired q-tiles (15-p, p) -> every block = 34 uniform steps, grid = 256 =
//   1 block/CU, zero drain. Q loads / O stores nontemporal (don't evict K/V).
//   Swapped QK^T keeps P lane-local feeding mfma_f32_16x16x16f16; row-sum l
//   via ones-column MFMA; defer-max rescale skip (THR=8, exp2 domain).

#define Bc 4
#define Lc 2048
#define Hc 8
#define Ec 64
#define TILEB 8192
#define NKV 32
#define BHB ((size_t)NKV * TILEB)      // 256 KB per bh
#define WSV ((size_t)32 * BHB)         // V images at +8 MB

using f32x4 = __attribute__((ext_vector_type(4))) float;
using f16x8 = __attribute__((ext_vector_type(8))) _Float16;
using f16x4 = __attribute__((ext_vector_type(4))) _Float16;
using hf16x2 = __fp16 __attribute__((ext_vector_type(2)));
using u32x4 = __attribute__((ext_vector_type(4))) unsigned int;

static __device__ __forceinline__ unsigned int pk2(float lo, float hi) {
    union { hf16x2 h; unsigned int u; } c;
    c.h = __builtin_amdgcn_cvt_pkrtz(lo, hi);
    return c.u;
}
static __device__ __forceinline__ u32x4 nt16(const void* p) {
    return __builtin_nontemporal_load((const u32x4*)p);
}

// ---------------- prepass: fp32 -> f16 fragment-ordered tile images ----------
__global__ __launch_bounds__(256)
void prep_kernel(const float* __restrict__ K, const float* __restrict__ V,
                 char* __restrict__ ws)
{
    __shared__ char kst[64 * 128];
    __shared__ char vst[64 * 144];
    __shared__ char vtt[64 * 128];

    const int bid = blockIdx.x;
    const int bh = bid >> 5, kt = bid & 31;
    const int b = bh >> 3, h = bh & 7;
    const int tid = threadIdx.x;
    const size_t base = (size_t)b * Lc * Hc * Ec + (size_t)h * Ec;

    {   // phase A: load (nontemporal - read once) + convert rows
        const int r = tid >> 2, q4 = tid & 3, c0 = 16 * q4;
        const float* kp = K + base + (size_t)(kt * 64 + r) * 512 + c0;
        const float* vp = V + base + (size_t)(kt * 64 + r) * 512 + c0;
        unsigned int wk[8], wv[8];
        #pragma unroll
        for (int i = 0; i < 4; ++i) {
            union { u32x4 v; float f[4]; } fk, fv;
            fk.v = nt16(kp + 4 * i);
            fv.v = nt16(vp + 4 * i);
            wk[2*i]   = pk2(fk.f[0], fk.f[1]); wk[2*i+1] = pk2(fk.f[2], fk.f[3]);
            wv[2*i]   = pk2(fv.f[0], fv.f[1]); wv[2*i+1] = pk2(fv.f[2], fv.f[3]);
        }
        *(uint4*)(kst + r * 128 + 2 * c0)      = *(uint4*)&wk[0];
        *(uint4*)(kst + r * 128 + 2 * c0 + 16) = *(uint4*)&wk[4];
        *(uint4*)(vst + r * 144 + 2 * c0)      = *(uint4*)&wv[0];
        *(uint4*)(vst + r * 144 + 2 * c0 + 16) = *(uint4*)&wv[4];
    }
    __syncthreads();
    {   // phase B: transpose V -> V^T
        const int e = tid >> 2, kq = tid & 3, kv0 = 16 * kq;
        unsigned int w[8];
        #pragma unroll
        for (int i = 0; i < 8; ++i) {
            unsigned int lo = *(const unsigned short*)(vst + (kv0 + 2*i)     * 144 + 2*e);
            unsigned int hi = *(const unsigned short*)(vst + (kv0 + 2*i + 1) * 144 + 2*e);
            w[i] = lo | (hi << 16);
        }
        *(uint4*)(vtt + e * 128 + 2 * kv0)      = *(uint4*)&w[0];
        *(uint4*)(vtt + e * 128 + 2 * kv0 + 16) = *(uint4*)&w[4];
    }
    __syncthreads();
    {   // phase C: emit fragment-ordered images
        const int lane = tid & 63, qq = tid >> 6;
        const int l15 = lane & 15, l4 = lane >> 4;
        char* ko = ws + (size_t)bh * BHB + (size_t)kt * TILEB;
        char* vo = ws + WSV + (size_t)bh * BHB + (size_t)kt * TILEB;
        uint4 k0 = *(const uint4*)(kst + (16 * qq + l15) * 128 + 16 * l4);
        uint4 k1 = *(const uint4*)(kst + (16 * qq + l15) * 128 + 64 + 16 * l4);
        *(uint4*)(ko + (2 * qq)     * 1024 + lane * 16) = k0;
        *(uint4*)(ko + (2 * qq + 1) * 1024 + lane * 16) = k1;
        unsigned long long vv[4];
        #pragma unroll
        for (int c = 0; c < 4; ++c)
            vv[c] = *(const unsigned long long*)(vtt + (16 * c + l15) * 128 + 32 * qq + 8 * l4);
        uint4 v01, v23;
        v01.x = (unsigned)vv[0]; v01.y = (unsigned)(vv[0] >> 32);
        v01.z = (unsigned)vv[1]; v01.w = (unsigned)(vv[1] >> 32);
        v23.x = (unsigned)vv[2]; v23.y = (unsigned)(vv[2] >> 32);
        v23.z = (unsigned)vv[3]; v23.w = (unsigned)(vv[3] >> 32);
        *(uint4*)(vo + (2 * qq)     * 1024 + lane * 16) = v01;
        *(uint4*)(vo + (2 * qq + 1) * 1024 + lane * 16) = v23;
    }
}

// ------------- main kernel: 8 waves, no barriers, L1 tile sharing ------------
__global__ __launch_bounds__(512, 2)
void fa_fwd_kernel(const float* __restrict__ Q, const char* __restrict__ ws,
                   float* __restrict__ Out)
{
    const int bid = blockIdx.x;
    const int bh  = bid & 31;                 // bh&7 == bid&7 -> XCD slot keeps 4 bh
    const int p   = bid >> 5;                 // 0..7 pair index
    const int b   = bh >> 3, h = bh & 7;

    const int tid  = threadIdx.x;
    const int wid  = tid >> 6;                // 0..7
    const int lane = tid & 63;
    const int l15  = lane & 15, l4 = lane >> 4;

    const size_t base = (size_t)b * Lc * Hc * Ec + (size_t)h * Ec;
    const char* kimg = ws + (size_t)bh * BHB + lane * 16;
    const char* vimg = ws + WSV + (size_t)bh * BHB + lane * 16;
    const float SL2E = 0.125f * 1.44269504088896340736f;

    f16x4 ones;
    {
        const _Float16 ov = (_Float16)((l15 == 0) ? 1.0f : 0.0f);
        ones[0] = ov; ones[1] = ov; ones[2] = ov; ones[3] = ov;
    }

    #pragma unroll 1
    for (int half = 0; half < 2; ++half) {
        const int qt = half ? p : (15 - p);       // long half first
        const int qrow0 = qt * 128 + 16 * wid;
        // waves 0-3: their last kv tile (base 128qt+64) is fully masked -> skip
        const int mysteps = 2 * qt + 1 + (wid >> 2);

        // Q fragment (B-operand, 16 rows), nontemporal, prescaled by scale*log2e
        f16x8 qa0, qa1;
        {
            const float* qpr = Q + base + (size_t)(qrow0 + l15) * 512 + 8 * l4;
            union { u32x4 v; float f[4]; } f0, f1, f2, f3;
            f0.v = nt16(qpr);      f1.v = nt16(qpr + 4);
            f2.v = nt16(qpr + 32); f3.v = nt16(qpr + 36);
            union { f16x8 v; unsigned int u[4]; } pk;
            pk.u[0] = pk2(f0.f[0] * SL2E, f0.f[1] * SL2E);
            pk.u[1] = pk2(f0.f[2] * SL2E, f0.f[3] * SL2E);
            pk.u[2] = pk2(f1.f[0] * SL2E, f1.f[1] * SL2E);
            pk.u[3] = pk2(f1.f[2] * SL2E, f1.f[3] * SL2E);
            qa0 = pk.v;
            pk.u[0] = pk2(f2.f[0] * SL2E, f2.f[1] * SL2E);
            pk.u[1] = pk2(f2.f[2] * SL2E, f2.f[3] * SL2E);
            pk.u[2] = pk2(f3.f[0] * SL2E, f3.f[1] * SL2E);
            pk.u[3] = pk2(f3.f[2] * SL2E, f3.f[3] * SL2E);
            qa1 = pk.v;
        }

        f32x4 o[4] = {};
        f32x4 ol = {};
        float m_run = -1e30f;

        uint4 kf[8], vf[8];
        #pragma unroll
        for (int j = 0; j < 8; ++j) kf[j] = *(const uint4*)(kimg + j * 1024);
        #pragma unroll
        for (int j = 0; j < 8; ++j) vf[j] = *(const uint4*)(vimg + j * 1024);

        #pragma unroll 1
        for (int kt = 0; kt < mysteps; ++kt) {
            // S^T = K·Q^T : lane holds S[kv=64kt+16n+4l4+r][q=qrow0+l15]
            f32x4 s[4];
            #pragma unroll
            for (int n = 0; n < 4; ++n) {
                union { uint4 u; f16x8 h; } a0, a1;
                a0.u = kf[2 * n]; a1.u = kf[2 * n + 1];
                f32x4 z = {0.f, 0.f, 0.f, 0.f};
                z = __builtin_amdgcn_mfma_f32_16x16x32_f16(a0.h, qa0, z, 0, 0, 0);
                z = __builtin_amdgcn_mfma_f32_16x16x32_f16(a1.h, qa1, z, 0, 0, 0);
                s[n] = z;
            }

            // register-prefetch next K tile
            if (kt + 1 < mysteps) {
                const char* kp = kimg + (size_t)(kt + 1) * TILEB;
                #pragma unroll
                for (int j = 0; j < 8; ++j) kf[j] = *(const uint4*)(kp + j * 1024);
            }

            if (kt == mysteps - 1) {   // causal mask (each wave's own last tile)
                const int q_g = qrow0 + l15;
                #pragma unroll
                for (int n = 0; n < 4; ++n) {
                    #pragma unroll
                    for (int r2 = 0; r2 < 4; ++r2) {
                        const int kv_g = kt * 64 + 16 * n + 4 * l4 + r2;
                        if (kv_g > q_g) s[n][r2] = -1e30f;
                    }
                }
            }

            // online softmax (scalar per q-col)
            float a0 = fmaxf(s[0][0], s[0][1]), a1 = fmaxf(s[0][2], s[0][3]);
            float a2 = fmaxf(s[1][0], s[1][1]), a3 = fmaxf(s[1][2], s[1][3]);
            float a4 = fmaxf(s[2][0], s[2][1]), a5 = fmaxf(s[2][2], s[2][3]);
            float a6 = fmaxf(s[3][0], s[3][1]), a7 = fmaxf(s[3][2], s[3][3]);
            float pmax = fmaxf(fmaxf(fmaxf(a0, a1), fmaxf(a2, a3)),
                               fmaxf(fmaxf(a4, a5), fmaxf(a6, a7)));
            pmax = fmaxf(pmax, __shfl_xor(pmax, 16, 64));
            pmax = fmaxf(pmax, __shfl_xor(pmax, 32, 64));

            if (!__all(pmax - m_run <= 8.0f)) {   // defer-max (THR=8)
                const float m_new = fmaxf(m_run, pmax);
                const float fac = __builtin_exp2f(m_run - m_new);
                m_run = m_new;
                float fr[4];
                #pragma unroll
                for (int r2 = 0; r2 < 4; ++r2) fr[r2] = __shfl(fac, 4 * l4 + r2, 64);
                #pragma unroll
                for (int c = 0; c < 4; ++c)
                    #pragma unroll
                    for (int r2 = 0; r2 < 4; ++r2) o[c][r2] *= fr[r2];
                #pragma unroll
                for (int r2 = 0; r2 < 4; ++r2) ol[r2] *= fr[r2];
            }

            // P = exp2(s - m), packed f16 (A-frag layout: k = 4*l4 + j)
            unsigned int ph[4][2];
            #pragma unroll
            for (int n = 0; n < 4; ++n) {
                float p0 = __builtin_exp2f(s[n][0] - m_run);
                float p1 = __builtin_exp2f(s[n][1] - m_run);
                float p2 = __builtin_exp2f(s[n][2] - m_run);
                float p3 = __builtin_exp2f(s[n][3] - m_run);
                ph[n][0] = pk2(p0, p1);
                ph[n][1] = pk2(p2, p3);
            }

            // O += P·V ; l += P·1
            #pragma unroll
            for (int m = 0; m < 4; ++m) {
                union { uint4 u; f16x4 h[2]; } w0, w1;
                w0.u = vf[2 * m]; w1.u = vf[2 * m + 1];
                union { f16x4 h; unsigned int u[2]; } pa;
                pa.u[0] = ph[m][0]; pa.u[1] = ph[m][1];
                ol   = __builtin_amdgcn_mfma_f32_16x16x16f16(pa.h, ones,    ol,   0, 0, 0);
                o[0] = __builtin_amdgcn_mfma_f32_16x16x16f16(pa.h, w0.h[0], o[0], 0, 0, 0);
                o[1] = __builtin_amdgcn_mfma_f32_16x16x16f16(pa.h, w0.h[1], o[1], 0, 0, 0);
                o[2] = __builtin_amdgcn_mfma_f32_16x16x16f16(pa.h, w1.h[0], o[2], 0, 0, 0);
                o[3] = __builtin_amdgcn_mfma_f32_16x16x16f16(pa.h, w1.h[1], o[3], 0, 0, 0);
            }

            // register-prefetch next V tile
            if (kt + 1 < mysteps) {
                const char* vp2 = vimg + (size_t)(kt + 1) * TILEB;
                #pragma unroll
                for (int j = 0; j < 8; ++j) vf[j] = *(const uint4*)(vp2 + j * 1024);
            }
        }

        // epilogue: normalize by l (col 0 of ol on l15==0 lanes), nt store fp32
        float ir[4];
        #pragma unroll
        for (int r2 = 0; r2 < 4; ++r2) {
            const float iv = 1.0f / ol[r2];
            ir[r2] = __shfl(iv, 16 * l4, 64);
        }
        float* op = Out + base;
        #pragma unroll
        for (int c = 0; c < 4; ++c)
            #pragma unroll
            for (int r2 = 0; r2 < 4; ++r2)
                __builtin_nontemporal_store(o[c][r2] * ir[r2],
                    op + (size_t)(qrow0 + 4 * l4 + r2) * 512 + 16 * c + l15);
    }
}

extern "C" void kernel_launch(void* const* d_in, const int* in_sizes, int n_in,
                              void* d_out, int out_size, void* d_ws, size_t ws_size,
                              hipStream_t stream) {
    const float* Q = (const float*)d_in[0];
    const float* K = (const float*)d_in[1];
    const float* V = (const float*)d_in[2];
    float* O = (float*)d_out;
    char* ws = (char*)d_ws;   // 16 MB fragment-ordered tile images
    hipLaunchKernelGGL(prep_kernel, dim3(32 * NKV), dim3(256), 0, stream, K, V, ws);
    hipLaunchKernelGGL(fa_fwd_kernel, dim3(256), dim3(512), 0, stream, Q, ws, O);
}

// Round 8
// 66.079 us; speedup vs baseline: 1.0616x; 1.0616x over previous
//
#include <hip/hip_runtime.h>

// Causal flash-attention forward. B=4, L=2048, H=8, E=64, fp32 in/out.
// Layout: [B, L, H, E] -> ((b*L + l)*H + h)*E + e ; row stride H*E = 512 floats.
//
// prepass: K and V^T -> f16 tiles in d_ws in FRAGMENT-CONSUMPTION order
//   (frag j of a 64x64 tile at tile_base + j*1024 + lane*16).
// main: 256-thread blocks (4 waves, NO barriers), all 4 waves on the SAME
//   64-row q-tile walking the SAME kv tiles (identical addresses -> L1 hits).
//   VGPR<=84 via launch_bounds(256,3) -> 3 blocks/CU = 12 waves/CU resident.
//   Register prefetch 1 tile ahead (V issued before next-K so vmcnt(8) waits
//   complete the right group). Swapped QK^T keeps P lane-local feeding
//   mfma_f32_16x16x16f16; row-sum l via ones-column MFMA; defer-max (THR=8).
//   Longest q-tiles dispatched first (short blocks fill the tail).

#define Bc 4
#define Lc 2048
#define Hc 8
#define Ec 64
#define TILEB 8192
#define NKV 32
#define BHB ((size_t)NKV * TILEB)      // 256 KB per bh
#define WSV ((size_t)32 * BHB)         // V images at +8 MB

using f32x4 = __attribute__((ext_vector_type(4))) float;
using f16x8 = __attribute__((ext_vector_type(8))) _Float16;
using f16x4 = __attribute__((ext_vector_type(4))) _Float16;
using hf16x2 = __fp16 __attribute__((ext_vector_type(2)));
using u32x4 = __attribute__((ext_vector_type(4))) unsigned int;

static __device__ __forceinline__ unsigned int pk2(float lo, float hi) {
    union { hf16x2 h; unsigned int u; } c;
    c.h = __builtin_amdgcn_cvt_pkrtz(lo, hi);
    return c.u;
}
static __device__ __forceinline__ u32x4 nt16(const void* p) {
    return __builtin_nontemporal_load((const u32x4*)p);
}

// ---------------- prepass: fp32 -> f16 fragment-ordered tile images ----------
__global__ __launch_bounds__(256)
void prep_kernel(const float* __restrict__ K, const float* __restrict__ V,
                 char* __restrict__ ws)
{
    __shared__ char kst[64 * 128];
    __shared__ char vst[64 * 144];
    __shared__ char vtt[64 * 128];

    const int bid = blockIdx.x;
    const int bh = bid >> 5, kt = bid & 31;
    const int b = bh >> 3, h = bh & 7;
    const int tid = threadIdx.x;
    const size_t base = (size_t)b * Lc * Hc * Ec + (size_t)h * Ec;

    {   // phase A: load (nontemporal - read once) + convert rows
        const int r = tid >> 2, q4 = tid & 3, c0 = 16 * q4;
        const float* kp = K + base + (size_t)(kt * 64 + r) * 512 + c0;
        const float* vp = V + base + (size_t)(kt * 64 + r) * 512 + c0;
        unsigned int wk[8], wv[8];
        #pragma unroll
        for (int i = 0; i < 4; ++i) {
            union { u32x4 v; float f[4]; } fk, fv;
            fk.v = nt16(kp + 4 * i);
            fv.v = nt16(vp + 4 * i);
            wk[2*i]   = pk2(fk.f[0], fk.f[1]); wk[2*i+1] = pk2(fk.f[2], fk.f[3]);
            wv[2*i]   = pk2(fv.f[0], fv.f[1]); wv[2*i+1] = pk2(fv.f[2], fv.f[3]);
        }
        *(uint4*)(kst + r * 128 + 2 * c0)      = *(uint4*)&wk[0];
        *(uint4*)(kst + r * 128 + 2 * c0 + 16) = *(uint4*)&wk[4];
        *(uint4*)(vst + r * 144 + 2 * c0)      = *(uint4*)&wv[0];
        *(uint4*)(vst + r * 144 + 2 * c0 + 16) = *(uint4*)&wv[4];
    }
    __syncthreads();
    {   // phase B: transpose V -> V^T
        const int e = tid >> 2, kq = tid & 3, kv0 = 16 * kq;
        unsigned int w[8];
        #pragma unroll
        for (int i = 0; i < 8; ++i) {
            unsigned int lo = *(const unsigned short*)(vst + (kv0 + 2*i)     * 144 + 2*e);
            unsigned int hi = *(const unsigned short*)(vst + (kv0 + 2*i + 1) * 144 + 2*e);
            w[i] = lo | (hi << 16);
        }
        *(uint4*)(vtt + e * 128 + 2 * kv0)      = *(uint4*)&w[0];
        *(uint4*)(vtt + e * 128 + 2 * kv0 + 16) = *(uint4*)&w[4];
    }
    __syncthreads();
    {   // phase C: emit fragment-ordered images
        const int lane = tid & 63, qq = tid >> 6;
        const int l15 = lane & 15, l4 = lane >> 4;
        char* ko = ws + (size_t)bh * BHB + (size_t)kt * TILEB;
        char* vo = ws + WSV + (size_t)bh * BHB + (size_t)kt * TILEB;
        uint4 k0 = *(const uint4*)(kst + (16 * qq + l15) * 128 + 16 * l4);
        uint4 k1 = *(const uint4*)(kst + (16 * qq + l15) * 128 + 64 + 16 * l4);
        *(uint4*)(ko + (2 * qq)     * 1024 + lane * 16) = k0;
        *(uint4*)(ko + (2 * qq + 1) * 1024 + lane * 16) = k1;
        unsigned long long vv[4];
        #pragma unroll
        for (int c = 0; c < 4; ++c)
            vv[c] = *(const unsigned long long*)(vtt + (16 * c + l15) * 128 + 32 * qq + 8 * l4);
        uint4 v01, v23;
        v01.x = (unsigned)vv[0]; v01.y = (unsigned)(vv[0] >> 32);
        v01.z = (unsigned)vv[1]; v01.w = (unsigned)(vv[1] >> 32);
        v23.x = (unsigned)vv[2]; v23.y = (unsigned)(vv[2] >> 32);
        v23.z = (unsigned)vv[3]; v23.w = (unsigned)(vv[3] >> 32);
        *(uint4*)(vo + (2 * qq)     * 1024 + lane * 16) = v01;
        *(uint4*)(vo + (2 * qq + 1) * 1024 + lane * 16) = v23;
    }
}

// ---- main kernel: 4 waves/block, no barriers, 3 blocks/CU, L1 tile sharing --
__global__ __launch_bounds__(256, 3)
void fa_fwd_kernel(const float* __restrict__ Q, const char* __restrict__ ws,
                   float* __restrict__ Out)
{
    const int bid = blockIdx.x;
    const int qi  = bid >> 5;                 // 0..31
    const int bh  = bid & 31;
    const int qt  = 31 - qi;                  // longest q-tiles first
    const int b   = bh >> 3, h = bh & 7;

    const int tid  = threadIdx.x;
    const int wid  = tid >> 6;                // 0..3
    const int lane = tid & 63;
    const int l15  = lane & 15, l4 = lane >> 4;

    const size_t base = (size_t)b * Lc * Hc * Ec + (size_t)h * Ec;
    const char* kimg = ws + (size_t)bh * BHB + lane * 16;
    const char* vimg = ws + WSV + (size_t)bh * BHB + lane * 16;
    const float SL2E = 0.125f * 1.44269504088896340736f;

    f16x4 ones;
    {
        const _Float16 ov = (_Float16)((l15 == 0) ? 1.0f : 0.0f);
        ones[0] = ov; ones[1] = ov; ones[2] = ov; ones[3] = ov;
    }

    const int qrow0 = qt * 64 + 16 * wid;
    const int mysteps = qt + 1;               // uniform within block

    // Q fragment (B-operand, 16 rows), nontemporal, prescaled by scale*log2e
    f16x8 qa0, qa1;
    {
        const float* qpr = Q + base + (size_t)(qrow0 + l15) * 512 + 8 * l4;
        union { u32x4 v; float f[4]; } f0, f1, f2, f3;
        f0.v = nt16(qpr);      f1.v = nt16(qpr + 4);
        f2.v = nt16(qpr + 32); f3.v = nt16(qpr + 36);
        union { f16x8 v; unsigned int u[4]; } pk;
        pk.u[0] = pk2(f0.f[0] * SL2E, f0.f[1] * SL2E);
        pk.u[1] = pk2(f0.f[2] * SL2E, f0.f[3] * SL2E);
        pk.u[2] = pk2(f1.f[0] * SL2E, f1.f[1] * SL2E);
        pk.u[3] = pk2(f1.f[2] * SL2E, f1.f[3] * SL2E);
        qa0 = pk.v;
        pk.u[0] = pk2(f2.f[0] * SL2E, f2.f[1] * SL2E);
        pk.u[1] = pk2(f2.f[2] * SL2E, f2.f[3] * SL2E);
        pk.u[2] = pk2(f3.f[0] * SL2E, f3.f[1] * SL2E);
        pk.u[3] = pk2(f3.f[2] * SL2E, f3.f[3] * SL2E);
        qa1 = pk.v;
    }

    f32x4 o[4] = {};
    f32x4 ol = {};
    float m_run = -1e30f;

    uint4 kf[8], vf[8];
    #pragma unroll
    for (int j = 0; j < 8; ++j) kf[j] = *(const uint4*)(kimg + j * 1024);
    #pragma unroll
    for (int j = 0; j < 8; ++j) vf[j] = *(const uint4*)(vimg + j * 1024);

    #pragma unroll 1
    for (int kt = 0; kt < mysteps; ++kt) {
        // S^T = K·Q^T : lane holds S[kv=64kt+16n+4l4+r][q=qrow0+l15]
        f32x4 s[4];
        #pragma unroll
        for (int n = 0; n < 4; ++n) {
            union { uint4 u; f16x8 h; } a0, a1;
            a0.u = kf[2 * n]; a1.u = kf[2 * n + 1];
            f32x4 z = {0.f, 0.f, 0.f, 0.f};
            z = __builtin_amdgcn_mfma_f32_16x16x32_f16(a0.h, qa0, z, 0, 0, 0);
            z = __builtin_amdgcn_mfma_f32_16x16x32_f16(a1.h, qa1, z, 0, 0, 0);
            s[n] = z;
        }

        // register-prefetch next K tile (issued AFTER prev V-prefetch group so
        // the vmcnt(8) wait before PV completes V, not K)
        if (kt + 1 < mysteps) {
            const char* kp = kimg + (size_t)(kt + 1) * TILEB;
            #pragma unroll
            for (int j = 0; j < 8; ++j) kf[j] = *(const uint4*)(kp + j * 1024);
        }

        if (kt == mysteps - 1) {   // causal mask on the diagonal tile
            const int q_g = qrow0 + l15;
            #pragma unroll
            for (int n = 0; n < 4; ++n) {
                #pragma unroll
                for (int r2 = 0; r2 < 4; ++r2) {
                    const int kv_g = kt * 64 + 16 * n + 4 * l4 + r2;
                    if (kv_g > q_g) s[n][r2] = -1e30f;
                }
            }
        }

        // online softmax (scalar per q-col)
        float a0 = fmaxf(s[0][0], s[0][1]), a1 = fmaxf(s[0][2], s[0][3]);
        float a2 = fmaxf(s[1][0], s[1][1]), a3 = fmaxf(s[1][2], s[1][3]);
        float a4 = fmaxf(s[2][0], s[2][1]), a5 = fmaxf(s[2][2], s[2][3]);
        float a6 = fmaxf(s[3][0], s[3][1]), a7 = fmaxf(s[3][2], s[3][3]);
        float pmax = fmaxf(fmaxf(fmaxf(a0, a1), fmaxf(a2, a3)),
                           fmaxf(fmaxf(a4, a5), fmaxf(a6, a7)));
        pmax = fmaxf(pmax, __shfl_xor(pmax, 16, 64));
        pmax = fmaxf(pmax, __shfl_xor(pmax, 32, 64));

        if (!__all(pmax - m_run <= 8.0f)) {   // defer-max (THR=8)
            const float m_new = fmaxf(m_run, pmax);
            const float fac = __builtin_exp2f(m_run - m_new);
            m_run = m_new;
            float fr[4];
            #pragma unroll
            for (int r2 = 0; r2 < 4; ++r2) fr[r2] = __shfl(fac, 4 * l4 + r2, 64);
            #pragma unroll
            for (int c = 0; c < 4; ++c)
                #pragma unroll
                for (int r2 = 0; r2 < 4; ++r2) o[c][r2] *= fr[r2];
            #pragma unroll
            for (int r2 = 0; r2 < 4; ++r2) ol[r2] *= fr[r2];
        }

        // P = exp2(s - m), packed f16 (A-frag layout: k = 4*l4 + j)
        unsigned int ph[4][2];
        #pragma unroll
        for (int n = 0; n < 4; ++n) {
            float p0 = __builtin_exp2f(s[n][0] - m_run);
            float p1 = __builtin_exp2f(s[n][1] - m_run);
            float p2 = __builtin_exp2f(s[n][2] - m_run);
            float p3 = __builtin_exp2f(s[n][3] - m_run);
            ph[n][0] = pk2(p0, p1);
            ph[n][1] = pk2(p2, p3);
        }

        // O += P·V ; l += P·1
        #pragma unroll
        for (int m = 0; m < 4; ++m) {
            union { uint4 u; f16x4 h[2]; } w0, w1;
            w0.u = vf[2 * m]; w1.u = vf[2 * m + 1];
            union { f16x4 h; unsigned int u[2]; } pa;
            pa.u[0] = ph[m][0]; pa.u[1] = ph[m][1];
            ol   = __builtin_amdgcn_mfma_f32_16x16x16f16(pa.h, ones,    ol,   0, 0, 0);
            o[0] = __builtin_amdgcn_mfma_f32_16x16x16f16(pa.h, w0.h[0], o[0], 0, 0, 0);
            o[1] = __builtin_amdgcn_mfma_f32_16x16x16f16(pa.h, w0.h[1], o[1], 0, 0, 0);
            o[2] = __builtin_amdgcn_mfma_f32_16x16x16f16(pa.h, w1.h[0], o[2], 0, 0, 0);
            o[3] = __builtin_amdgcn_mfma_f32_16x16x16f16(pa.h, w1.h[1], o[3], 0, 0, 0);
        }

        // register-prefetch next V tile
        if (kt + 1 < mysteps) {
            const char* vp2 = vimg + (size_t)(kt + 1) * TILEB;
            #pragma unroll
            for (int j = 0; j < 8; ++j) vf[j] = *(const uint4*)(vp2 + j * 1024);
        }
    }

    // epilogue: normalize by l (col 0 of ol on l15==0 lanes), nt store fp32
    float ir[4];
    #pragma unroll
    for (int r2 = 0; r2 < 4; ++r2) {
        const float iv = 1.0f / ol[r2];
        ir[r2] = __shfl(iv, 16 * l4, 64);
    }
    float* op = Out + base;
    #pragma unroll
    for (int c = 0; c < 4; ++c)
        #pragma unroll
        for (int r2 = 0; r2 < 4; ++r2)
            __builtin_nontemporal_store(o[c][r2] * ir[r2],
                op + (size_t)(qrow0 + 4 * l4 + r2) * 512 + 16 * c + l15);
}

extern "C" void kernel_launch(void* const* d_in, const int* in_sizes, int n_in,
                              void* d_out, int out_size, void* d_ws, size_t ws_size,
                              hipStream_t stream) {
    const float* Q = (const float*)d_in[0];
    const float* K = (const float*)d_in[1];
    const float* V = (const float*)d_in[2];
    float* O = (float*)d_out;
    char* ws = (char*)d_ws;   // 16 MB fragment-ordered tile images
    hipLaunchKernelGGL(prep_kernel, dim3(32 * NKV), dim3(256), 0, stream, K, V, ws);
    hipLaunchKernelGGL(fa_fwd_kernel, dim3(32 * 32), dim3(256), 0, stream, Q, ws, O);
}